// Round 1
// baseline (620.435 us; speedup 1.0000x reference)
//
#include <hip/hip_runtime.h>
#include <hip/hip_bf16.h>
#include <hip/hip_fp16.h>

typedef _Float16 f16;
typedef f16 f16x2 __attribute__((ext_vector_type(2)));
typedef f16 f16x4 __attribute__((ext_vector_type(4)));
typedef f16 f16x8 __attribute__((ext_vector_type(8)));
typedef float f32x4 __attribute__((ext_vector_type(4)));

#define B_ 64
#define S_ 256
#define E_ 4
#define I_ 512
#define H_ 512
#define M_ (B_*S_)   // 16384
#define N_ (E_*H_)   // 2048
#define K_ 512

// ---------------- cast / precompute kernels ----------------

// x (f32, 8388608) -> f16, 8 elems/thread
__global__ void cast_x(const float* __restrict__ x, f16* __restrict__ x16) {
    int gid = blockIdx.x * blockDim.x + threadIdx.x;
    const float4* src = (const float4*)x + (size_t)gid * 2;
    float4 a = src[0], b = src[1];
    f16x8 v = { (f16)a.x,(f16)a.y,(f16)a.z,(f16)a.w,
                (f16)b.x,(f16)b.y,(f16)b.z,(f16)b.w };
    *((f16x8*)x16 + gid) = v;
}

// W_hh (f32, 262144) -> f16, 8 elems/thread
__global__ void cast_w(const float* __restrict__ w, f16* __restrict__ w16) {
    int gid = blockIdx.x * blockDim.x + threadIdx.x;
    const float4* src = (const float4*)w + (size_t)gid * 2;
    float4 a = src[0], b = src[1];
    f16x8 v = { (f16)a.x,(f16)a.y,(f16)a.z,(f16)a.w,
                (f16)b.x,(f16)b.y,(f16)b.z,(f16)b.w };
    *((f16x8*)w16 + gid) = v;
}

// BT[n][i] = r[e][i] * W_ih[g][i], n = e*512+g. grid 2048 x 128 threads, 4 i/thread
__global__ void cast_bt(const float* __restrict__ Wih, const float* __restrict__ r,
                        f16* __restrict__ BT) {
    int n = blockIdx.x;
    int e = n >> 9, g = n & 511;
    int i = threadIdx.x * 4;
    float4 wv = *(const float4*)&Wih[(size_t)g * I_ + i];
    float4 rv = *(const float4*)&r[(size_t)e * I_ + i];
    f16x4 o = { (f16)(wv.x * rv.x), (f16)(wv.y * rv.y),
                (f16)(wv.z * rv.z), (f16)(wv.w * rv.w) };
    *(f16x4*)&BT[(size_t)n * I_ + i] = o;
}

// ---------------- phase 1: f16 MFMA GEMM ----------------
// C[m][n] = sum_k A[m][k] * BT[n][k];  M=16384, N=2048, K=512
// 128x128 tile, BK=32, 256 threads (4 waves in 2x2 quadrants)
#define LDK 40   // padded LDS leading dim (f16 units)

__global__ __launch_bounds__(256) void gemm16(const f16* __restrict__ A,
                                              const f16* __restrict__ Bt,
                                              float* __restrict__ C) {
    __shared__ f16 sA[128 * LDK];
    __shared__ f16 sB[128 * LDK];
    const int tid = threadIdx.x;
    const int w = tid >> 6, l = tid & 63;
    const int tn = blockIdx.x & 15, tm = blockIdx.x >> 4;
    const int m0 = tm * 128, n0 = tn * 128;
    const int srow = tid >> 2;            // 0..63
    const int scol = (tid & 3) * 8;       // 0,8,16,24
    const int wm = (w >> 1) * 64, wn = (w & 1) * 64;
    const int fr = l & 15;
    const int fk = (l >> 4) * 8;

    f32x4 acc[4][4] = {};

    for (int k0 = 0; k0 < K_; k0 += 32) {
        uint4 a0 = *(const uint4*)&A[(size_t)(m0 + srow) * K_ + k0 + scol];
        uint4 a1 = *(const uint4*)&A[(size_t)(m0 + srow + 64) * K_ + k0 + scol];
        uint4 b0 = *(const uint4*)&Bt[(size_t)(n0 + srow) * K_ + k0 + scol];
        uint4 b1 = *(const uint4*)&Bt[(size_t)(n0 + srow + 64) * K_ + k0 + scol];
        __syncthreads();  // protect previous iteration's fragment reads
        *(uint4*)&sA[srow * LDK + scol] = a0;
        *(uint4*)&sA[(srow + 64) * LDK + scol] = a1;
        *(uint4*)&sB[srow * LDK + scol] = b0;
        *(uint4*)&sB[(srow + 64) * LDK + scol] = b1;
        __syncthreads();
        f16x8 af[4], bf[4];
        #pragma unroll
        for (int mi = 0; mi < 4; ++mi)
            af[mi] = *(const f16x8*)&sA[(wm + mi * 16 + fr) * LDK + fk];
        #pragma unroll
        for (int ni = 0; ni < 4; ++ni)
            bf[ni] = *(const f16x8*)&sB[(wn + ni * 16 + fr) * LDK + fk];
        #pragma unroll
        for (int mi = 0; mi < 4; ++mi)
            #pragma unroll
            for (int ni = 0; ni < 4; ++ni)
                acc[mi][ni] = __builtin_amdgcn_mfma_f32_16x16x32_f16(
                    af[mi], bf[ni], acc[mi][ni], 0, 0, 0);
    }
    // D: col = lane&15, row = (lane>>4)*4 + j   [guide §3, m89-verified]
    #pragma unroll
    for (int mi = 0; mi < 4; ++mi)
        #pragma unroll
        for (int ni = 0; ni < 4; ++ni) {
            int row = m0 + wm + mi * 16 + (l >> 4) * 4;
            int col = n0 + wn + ni * 16 + fr;
            #pragma unroll
            for (int j = 0; j < 4; ++j)
                C[(size_t)(row + j) * N_ + col] = acc[mi][ni][j];
        }
}

// ---------------- phase 2: recurrent scan ----------------
// One block per (b,e) chain. 512 threads = 8 waves.
// W_hh rows 0..383 in registers (wave w holds k-range [64w,64w+64), lane holds
// 6 rows r=l+64j as 192 packed-u32 VGPRs). Rows 384..511 in LDS as
// Wl[kp][g] = (W[384+g][2kp], W[384+g][2kp+1]).
// h kept as packed f16 in LDS; dot products via v_dot2_f32_f16.

#define SCAN_LDS_BYTES (131072 + 16384 + 8192 + 1024)  // Wl + parts + partsL + hbuf

__device__ __forceinline__ float fdot2u(uint32_t wbits, f16x2 h, float acc) {
    return __builtin_amdgcn_fdot2(__builtin_bit_cast(f16x2, wbits), h, acc, false);
}

__global__ __launch_bounds__(512) void scan_rnn(const f16* __restrict__ W16,
                                                const float* __restrict__ s_in,
                                                float* __restrict__ out,
                                                float* __restrict__ hidden) {
    extern __shared__ char smem[];
    uint32_t* Wl     = (uint32_t*)smem;                 // [256 kp][128 g]  128 KB
    float*    parts  = (float*)(smem + 131072);         // [8][512]          16 KB
    float*    partsL = (float*)(smem + 147456);         // [16][128]          8 KB
    uint32_t* hw32   = (uint32_t*)(smem + 155648);      // [256] packed h     1 KB
    f16*      hbuf   = (f16*)hw32;

    const int tid = threadIdx.x;
    const int w = tid >> 6, l = tid & 63;
    const int sel = l >> 5;        // half-wave: which kp parity this lane covers
    const int q = l & 31;          // row-quad index for LDS rows
    const int b = blockIdx.x >> 2, e = blockIdx.x & 3;

    // ---- load register-resident W rows ----
    uint32_t wreg[6][32];
    {
        const uint32_t* Wp = (const uint32_t*)W16;      // [512 rows][256 u32]
        #pragma unroll
        for (int j = 0; j < 6; ++j) {
            const uint32_t* rowp = Wp + (size_t)(l + 64 * j) * 256 + 32 * w;
            #pragma unroll
            for (int c = 0; c < 32; c += 4) {
                uint4 v = *(const uint4*)&rowp[c];
                wreg[j][c + 0] = v.x; wreg[j][c + 1] = v.y;
                wreg[j][c + 2] = v.z; wreg[j][c + 3] = v.w;
            }
        }
        // ---- stage LDS-resident W rows 384..511 ----
        int g = tid & 127, kp0 = (tid >> 7) * 64;
        const uint32_t* rp = Wp + (size_t)(384 + g) * 256;
        for (int kp = kp0; kp < kp0 + 64; ++kp)
            Wl[kp * 128 + g] = rp[kp];
    }
    if (tid < 256) hw32[tid] = 0;   // h0 = 0
    const float s_reg = s_in[(size_t)e * H_ + tid];
    float* obase = out + ((size_t)b * S_ * E_ + e) * 512;   // + t*2048 + tid
    __syncthreads();

    float hcur = 0.f;
    for (int t = 0; t < S_; ++t) {
        float inp = obase[(size_t)t * (E_ * 512) + tid];   // pre-activation from GEMM
        float a0 = 0, a1 = 0, a2 = 0, a3 = 0, a4 = 0, a5 = 0;
        float q0 = 0, q1 = 0, q2 = 0, q3 = 0;
        #pragma unroll
        for (int c8 = 0; c8 < 8; ++c8) {
            const int kpb = w * 32 + c8 * 4;
            uint4 hv = *(const uint4*)&hw32[kpb];          // uniform -> broadcast
            uint32_t hA = sel ? hv.y : hv.x;
            uint32_t hB = sel ? hv.w : hv.z;
            f16x2 h2A = __builtin_bit_cast(f16x2, hA);
            f16x2 h2B = __builtin_bit_cast(f16x2, hB);
            uint4 wA = *(const uint4*)&Wl[(kpb + sel) * 128 + 4 * q];
            uint4 wB = *(const uint4*)&Wl[(kpb + 2 + sel) * 128 + 4 * q];
            q0 = fdot2u(wA.x, h2A, q0); q1 = fdot2u(wA.y, h2A, q1);
            q2 = fdot2u(wA.z, h2A, q2); q3 = fdot2u(wA.w, h2A, q3);
            q0 = fdot2u(wB.x, h2B, q0); q1 = fdot2u(wB.y, h2B, q1);
            q2 = fdot2u(wB.z, h2B, q2); q3 = fdot2u(wB.w, h2B, q3);
            uint32_t hcc0 = hv.x, hcc1 = hv.y, hcc2 = hv.z, hcc3 = hv.w;
            f16x2 h20 = __builtin_bit_cast(f16x2, hcc0);
            f16x2 h21 = __builtin_bit_cast(f16x2, hcc1);
            f16x2 h22 = __builtin_bit_cast(f16x2, hcc2);
            f16x2 h23 = __builtin_bit_cast(f16x2, hcc3);
            a0 = fdot2u(wreg[0][c8*4+0], h20, a0); a0 = fdot2u(wreg[0][c8*4+1], h21, a0);
            a0 = fdot2u(wreg[0][c8*4+2], h22, a0); a0 = fdot2u(wreg[0][c8*4+3], h23, a0);
            a1 = fdot2u(wreg[1][c8*4+0], h20, a1); a1 = fdot2u(wreg[1][c8*4+1], h21, a1);
            a1 = fdot2u(wreg[1][c8*4+2], h22, a1); a1 = fdot2u(wreg[1][c8*4+3], h23, a1);
            a2 = fdot2u(wreg[2][c8*4+0], h20, a2); a2 = fdot2u(wreg[2][c8*4+1], h21, a2);
            a2 = fdot2u(wreg[2][c8*4+2], h22, a2); a2 = fdot2u(wreg[2][c8*4+3], h23, a2);
            a3 = fdot2u(wreg[3][c8*4+0], h20, a3); a3 = fdot2u(wreg[3][c8*4+1], h21, a3);
            a3 = fdot2u(wreg[3][c8*4+2], h22, a3); a3 = fdot2u(wreg[3][c8*4+3], h23, a3);
            a4 = fdot2u(wreg[4][c8*4+0], h20, a4); a4 = fdot2u(wreg[4][c8*4+1], h21, a4);
            a4 = fdot2u(wreg[4][c8*4+2], h22, a4); a4 = fdot2u(wreg[4][c8*4+3], h23, a4);
            a5 = fdot2u(wreg[5][c8*4+0], h20, a5); a5 = fdot2u(wreg[5][c8*4+1], h21, a5);
            a5 = fdot2u(wreg[5][c8*4+2], h22, a5); a5 = fdot2u(wreg[5][c8*4+3], h23, a5);
        }
        // publish partials
        parts[w * 512 +   0 + l] = a0;
        parts[w * 512 +  64 + l] = a1;
        parts[w * 512 + 128 + l] = a2;
        parts[w * 512 + 192 + l] = a3;
        parts[w * 512 + 256 + l] = a4;
        parts[w * 512 + 320 + l] = a5;
        *(float4*)&partsL[(2 * w + sel) * 128 + 4 * q] = make_float4(q0, q1, q2, q3);
        __syncthreads();
        // reduce + activate: thread tid owns output row tid
        float pre = inp;
        if (tid < 384) {
            #pragma unroll
            for (int ww = 0; ww < 8; ++ww) pre += parts[ww * 512 + tid];
        } else {
            int rr = tid - 384;
            #pragma unroll
            for (int vw = 0; vw < 16; ++vw) pre += partsL[vw * 128 + rr];
        }
        hcur = tanhf(pre * s_reg);
        obase[(size_t)t * (E_ * 512) + tid] = hcur;
        hbuf[tid] = (f16)hcur;
        __syncthreads();
    }
    // hidden: (1, E, B, H)
    hidden[((size_t)e * B_ + b) * H_ + tid] = hcur;
}

// ---------------- launch ----------------
extern "C" void kernel_launch(void* const* d_in, const int* in_sizes, int n_in,
                              void* d_out, int out_size, void* d_ws, size_t ws_size,
                              hipStream_t stream) {
    const float* x   = (const float*)d_in[0];
    const float* Wih = (const float*)d_in[1];
    const float* Whh = (const float*)d_in[2];
    const float* r   = (const float*)d_in[3];
    const float* s   = (const float*)d_in[4];
    float* out = (float*)d_out;
    float* hidden = out + (size_t)B_ * S_ * E_ * H_;

    f16* x16 = (f16*)d_ws;                               // 16 MB
    f16* BT  = (f16*)((char*)d_ws + 16777216);           //  2 MB
    f16* W16 = (f16*)((char*)d_ws + 18874368);           // 0.5 MB

    hipLaunchKernelGGL(cast_x,  dim3(4096), dim3(256), 0, stream, x, x16);
    hipLaunchKernelGGL(cast_w,  dim3(128),  dim3(256), 0, stream, Whh, W16);
    hipLaunchKernelGGL(cast_bt, dim3(2048), dim3(128), 0, stream, Wih, r, BT);
    hipLaunchKernelGGL(gemm16,  dim3(2048), dim3(256), 0, stream, x16, BT, out);

    hipFuncSetAttribute((const void*)scan_rnn,
                        hipFuncAttributeMaxDynamicSharedMemorySize, SCAN_LDS_BYTES);
    hipLaunchKernelGGL(scan_rnn, dim3(256), dim3(512), SCAN_LDS_BYTES, stream,
                       W16, s, out, hidden);
}

// Round 8
// 619.493 us; speedup vs baseline: 1.0015x; 1.0015x over previous
//
#include <hip/hip_runtime.h>
#include <hip/hip_bf16.h>
#include <hip/hip_fp16.h>

typedef _Float16 f16;
typedef f16 f16x2 __attribute__((ext_vector_type(2)));
typedef f16 f16x4 __attribute__((ext_vector_type(4)));
typedef f16 f16x8 __attribute__((ext_vector_type(8)));
typedef float f32x4 __attribute__((ext_vector_type(4)));

#define B_ 64
#define S_ 256
#define E_ 4
#define I_ 512
#define H_ 512
#define M_ (B_*S_)   // 16384
#define N_ (E_*H_)   // 2048
#define K_ 512

// ---------------- cast / precompute kernels ----------------

__global__ void cast_x(const float* __restrict__ x, f16* __restrict__ x16) {
    int gid = blockIdx.x * blockDim.x + threadIdx.x;
    const float4* src = (const float4*)x + (size_t)gid * 2;
    float4 a = src[0], b = src[1];
    f16x8 v = { (f16)a.x,(f16)a.y,(f16)a.z,(f16)a.w,
                (f16)b.x,(f16)b.y,(f16)b.z,(f16)b.w };
    *((f16x8*)x16 + gid) = v;
}

__global__ void cast_w(const float* __restrict__ w, f16* __restrict__ w16) {
    int gid = blockIdx.x * blockDim.x + threadIdx.x;
    const float4* src = (const float4*)w + (size_t)gid * 2;
    float4 a = src[0], b = src[1];
    f16x8 v = { (f16)a.x,(f16)a.y,(f16)a.z,(f16)a.w,
                (f16)b.x,(f16)b.y,(f16)b.z,(f16)b.w };
    *((f16x8*)w16 + gid) = v;
}

// BT[n][i] = r[e][i] * W_ih[g][i], n = e*512+g
__global__ void cast_bt(const float* __restrict__ Wih, const float* __restrict__ r,
                        f16* __restrict__ BT) {
    int n = blockIdx.x;
    int e = n >> 9, g = n & 511;
    int i = threadIdx.x * 4;
    float4 wv = *(const float4*)&Wih[(size_t)g * I_ + i];
    float4 rv = *(const float4*)&r[(size_t)e * I_ + i];
    f16x4 o = { (f16)(wv.x * rv.x), (f16)(wv.y * rv.y),
                (f16)(wv.z * rv.z), (f16)(wv.w * rv.w) };
    *(f16x4*)&BT[(size_t)n * I_ + i] = o;
}

// ---------------- phase 1: f16 MFMA GEMM (unchanged this round) ----------------
#define LDK 40

__global__ __launch_bounds__(256) void gemm16(const f16* __restrict__ A,
                                              const f16* __restrict__ Bt,
                                              float* __restrict__ C) {
    __shared__ f16 sA[128 * LDK];
    __shared__ f16 sB[128 * LDK];
    const int tid = threadIdx.x;
    const int w = tid >> 6, l = tid & 63;
    const int tn = blockIdx.x & 15, tm = blockIdx.x >> 4;
    const int m0 = tm * 128, n0 = tn * 128;
    const int srow = tid >> 2;
    const int scol = (tid & 3) * 8;
    const int wm = (w >> 1) * 64, wn = (w & 1) * 64;
    const int fr = l & 15;
    const int fk = (l >> 4) * 8;

    f32x4 acc[4][4] = {};

    for (int k0 = 0; k0 < K_; k0 += 32) {
        uint4 a0 = *(const uint4*)&A[(size_t)(m0 + srow) * K_ + k0 + scol];
        uint4 a1 = *(const uint4*)&A[(size_t)(m0 + srow + 64) * K_ + k0 + scol];
        uint4 b0 = *(const uint4*)&Bt[(size_t)(n0 + srow) * K_ + k0 + scol];
        uint4 b1 = *(const uint4*)&Bt[(size_t)(n0 + srow + 64) * K_ + k0 + scol];
        __syncthreads();
        *(uint4*)&sA[srow * LDK + scol] = a0;
        *(uint4*)&sA[(srow + 64) * LDK + scol] = a1;
        *(uint4*)&sB[srow * LDK + scol] = b0;
        *(uint4*)&sB[(srow + 64) * LDK + scol] = b1;
        __syncthreads();
        f16x8 af[4], bf[4];
        #pragma unroll
        for (int mi = 0; mi < 4; ++mi)
            af[mi] = *(const f16x8*)&sA[(wm + mi * 16 + fr) * LDK + fk];
        #pragma unroll
        for (int ni = 0; ni < 4; ++ni)
            bf[ni] = *(const f16x8*)&sB[(wn + ni * 16 + fr) * LDK + fk];
        #pragma unroll
        for (int mi = 0; mi < 4; ++mi)
            #pragma unroll
            for (int ni = 0; ni < 4; ++ni)
                acc[mi][ni] = __builtin_amdgcn_mfma_f32_16x16x32_f16(
                    af[mi], bf[ni], acc[mi][ni], 0, 0, 0);
    }
    #pragma unroll
    for (int mi = 0; mi < 4; ++mi)
        #pragma unroll
        for (int ni = 0; ni < 4; ++ni) {
            int row = m0 + wm + mi * 16 + (l >> 4) * 4;
            int col = n0 + wn + ni * 16 + fr;
            #pragma unroll
            for (int j = 0; j < 4; ++j)
                C[(size_t)(row + j) * N_ + col] = acc[mi][ni][j];
        }
}

// ---------------- phase 2: recurrent scan ----------------
// One block per (b,e) chain, 512 threads = 8 waves, 1 block/CU.
// W_hh rows 0..383 register-resident: wave w holds k-range [64w,64w+64),
// lane l holds rows l+64j (j=0..5) as uint4 wr[6][8] (192 VGPRs of packed f16).
// Rows 384..511 in LDS: Wl[kp][g] = packed (W[384+g][2kp],W[384+g][2kp+1]).

#define SCAN_LDS_BYTES (131072 + 16384 + 8192 + 1024)

__device__ __forceinline__ float fdot2u(uint32_t wbits, f16x2 h, float acc) {
    return __builtin_amdgcn_fdot2(__builtin_bit_cast(f16x2, wbits), h, acc, false);
}

__device__ __forceinline__ float fast_tanh(float x) {
    // tanh(x) = 1 - 2/(exp(2x)+1); v_exp_f32 + v_rcp_f32, ~1e-6 abs err
    float e = __expf(2.0f * x);
    return 1.0f - 2.0f * __builtin_amdgcn_rcpf(e + 1.0f);
}

__global__ __launch_bounds__(512, 2) void scan_rnn(const f16* __restrict__ W16,
                                                   const float* __restrict__ s_in,
                                                   float* __restrict__ out,
                                                   float* __restrict__ hidden) {
    extern __shared__ char smem[];
    uint32_t* Wl     = (uint32_t*)smem;                 // [256 kp][128 g]  128 KB
    float*    parts  = (float*)(smem + 131072);         // [8][512]          16 KB
    float*    partsL = (float*)(smem + 147456);         // [16][128]          8 KB
    uint32_t* hw32   = (uint32_t*)(smem + 155648);      // [256] packed h     1 KB
    f16*      hbuf   = (f16*)hw32;

    const int tid = threadIdx.x;
    const int w = tid >> 6, l = tid & 63;
    const int sel = l >> 5;
    const int q = l & 31;
    const int b = blockIdx.x >> 2, e = blockIdx.x & 3;

    // ---- register-resident W rows (all indices compile-time static) ----
    uint4 wr[6][8];
    {
        const uint4* Wp4 = (const uint4*)W16;           // [512 rows][64 uint4]
        #pragma unroll
        for (int j = 0; j < 6; ++j) {
            const uint4* rowp = Wp4 + (size_t)(l + 64 * j) * 64 + 8 * w;
            #pragma unroll
            for (int c = 0; c < 8; ++c)
                wr[j][c] = rowp[c];
        }
        // ---- LDS-resident W rows 384..511 ----
        const uint32_t* Wp = (const uint32_t*)W16;
        int g = tid & 127, kp0 = (tid >> 7) * 64;
        const uint32_t* rp = Wp + (size_t)(384 + g) * 256;
        #pragma unroll 4
        for (int kp = kp0; kp < kp0 + 64; ++kp)
            Wl[kp * 128 + g] = rp[kp];
    }
    if (tid < 256) hw32[tid] = 0;
    const float s_reg = s_in[(size_t)e * H_ + tid];
    float* obase = out + ((size_t)b * S_ * E_ + e) * 512;
    __syncthreads();

    float hcur = 0.f;
    float inp = obase[tid];   // t = 0 pre-activation
    for (int t = 0; t < S_; ++t) {
        // prefetch next step's pre-activation; hides under the dot phase
        float inp_next = obase[(size_t)(t < S_ - 1 ? t + 1 : t) * (E_ * 512) + tid];
        float a0 = 0, a1 = 0, a2 = 0, a3 = 0, a4 = 0, a5 = 0;
        float q0 = 0, q1 = 0, q2 = 0, q3 = 0;
        #pragma unroll
        for (int c8 = 0; c8 < 8; ++c8) {
            const int kpb = w * 32 + c8 * 4;
            uint4 hv = *(const uint4*)&hw32[kpb];        // wave-uniform -> broadcast
            uint32_t hA = sel ? hv.y : hv.x;
            uint32_t hB = sel ? hv.w : hv.z;
            f16x2 h2A = __builtin_bit_cast(f16x2, hA);
            f16x2 h2B = __builtin_bit_cast(f16x2, hB);
            uint4 wA = *(const uint4*)&Wl[(kpb + sel) * 128 + 4 * q];
            uint4 wB = *(const uint4*)&Wl[(kpb + 2 + sel) * 128 + 4 * q];
            q0 = fdot2u(wA.x, h2A, q0); q1 = fdot2u(wA.y, h2A, q1);
            q2 = fdot2u(wA.z, h2A, q2); q3 = fdot2u(wA.w, h2A, q3);
            q0 = fdot2u(wB.x, h2B, q0); q1 = fdot2u(wB.y, h2B, q1);
            q2 = fdot2u(wB.z, h2B, q2); q3 = fdot2u(wB.w, h2B, q3);
            f16x2 h20 = __builtin_bit_cast(f16x2, hv.x);
            f16x2 h21 = __builtin_bit_cast(f16x2, hv.y);
            f16x2 h22 = __builtin_bit_cast(f16x2, hv.z);
            f16x2 h23 = __builtin_bit_cast(f16x2, hv.w);
            a0 = fdot2u(wr[0][c8].x, h20, a0); a0 = fdot2u(wr[0][c8].y, h21, a0);
            a0 = fdot2u(wr[0][c8].z, h22, a0); a0 = fdot2u(wr[0][c8].w, h23, a0);
            a1 = fdot2u(wr[1][c8].x, h20, a1); a1 = fdot2u(wr[1][c8].y, h21, a1);
            a1 = fdot2u(wr[1][c8].z, h22, a1); a1 = fdot2u(wr[1][c8].w, h23, a1);
            a2 = fdot2u(wr[2][c8].x, h20, a2); a2 = fdot2u(wr[2][c8].y, h21, a2);
            a2 = fdot2u(wr[2][c8].z, h22, a2); a2 = fdot2u(wr[2][c8].w, h23, a2);
            a3 = fdot2u(wr[3][c8].x, h20, a3); a3 = fdot2u(wr[3][c8].y, h21, a3);
            a3 = fdot2u(wr[3][c8].z, h22, a3); a3 = fdot2u(wr[3][c8].w, h23, a3);
            a4 = fdot2u(wr[4][c8].x, h20, a4); a4 = fdot2u(wr[4][c8].y, h21, a4);
            a4 = fdot2u(wr[4][c8].z, h22, a4); a4 = fdot2u(wr[4][c8].w, h23, a4);
            a5 = fdot2u(wr[5][c8].x, h20, a5); a5 = fdot2u(wr[5][c8].y, h21, a5);
            a5 = fdot2u(wr[5][c8].z, h22, a5); a5 = fdot2u(wr[5][c8].w, h23, a5);
        }
        parts[w * 512 +   0 + l] = a0;
        parts[w * 512 +  64 + l] = a1;
        parts[w * 512 + 128 + l] = a2;
        parts[w * 512 + 192 + l] = a3;
        parts[w * 512 + 256 + l] = a4;
        parts[w * 512 + 320 + l] = a5;
        *(float4*)&partsL[(2 * w + sel) * 128 + 4 * q] = make_float4(q0, q1, q2, q3);
        __syncthreads();
        float pre = inp;
        if (tid < 384) {
            #pragma unroll
            for (int ww = 0; ww < 8; ++ww) pre += parts[ww * 512 + tid];
        } else {
            int rr = tid - 384;
            #pragma unroll
            for (int vw = 0; vw < 16; ++vw) pre += partsL[vw * 128 + rr];
        }
        hcur = fast_tanh(pre * s_reg);
        obase[(size_t)t * (E_ * 512) + tid] = hcur;
        hbuf[tid] = (f16)hcur;
        inp = inp_next;
        __syncthreads();
    }
    hidden[((size_t)e * B_ + b) * H_ + tid] = hcur;
}

// ---------------- launch ----------------
extern "C" void kernel_launch(void* const* d_in, const int* in_sizes, int n_in,
                              void* d_out, int out_size, void* d_ws, size_t ws_size,
                              hipStream_t stream) {
    const float* x   = (const float*)d_in[0];
    const float* Wih = (const float*)d_in[1];
    const float* Whh = (const float*)d_in[2];
    const float* r   = (const float*)d_in[3];
    const float* s   = (const float*)d_in[4];
    float* out = (float*)d_out;
    float* hidden = out + (size_t)B_ * S_ * E_ * H_;

    f16* x16 = (f16*)d_ws;                               // 16 MB
    f16* BT  = (f16*)((char*)d_ws + 16777216);           //  2 MB
    f16* W16 = (f16*)((char*)d_ws + 18874368);           // 0.5 MB

    hipLaunchKernelGGL(cast_x,  dim3(4096), dim3(256), 0, stream, x, x16);
    hipLaunchKernelGGL(cast_w,  dim3(128),  dim3(256), 0, stream, Whh, W16);
    hipLaunchKernelGGL(cast_bt, dim3(2048), dim3(128), 0, stream, Wih, r, BT);
    hipLaunchKernelGGL(gemm16,  dim3(2048), dim3(256), 0, stream, x16, BT, out);

    hipFuncSetAttribute((const void*)scan_rnn,
                        hipFuncAttributeMaxDynamicSharedMemorySize, SCAN_LDS_BYTES);
    hipLaunchKernelGGL(scan_rnn, dim3(256), dim3(512), SCAN_LDS_BYTES, stream,
                       W16, s, out, hidden);
}